// Round 6
// baseline (1239.737 us; speedup 1.0000x reference)
//
#include <hip/hip_runtime.h>

#define BD 32768
#define DD 2048
#define LN_EPS 1e-5f
#define MARGIN 0.03f
#define UCAP 8192          // max rows re-checked at split precision (expected ~2k)
#define IDX_CAP 33280      // 32768 + 2*256 padding (256-tile segments)

typedef unsigned short u16;
typedef unsigned int u32;
typedef __bf16 bf16x8 __attribute__((ext_vector_type(8)));
typedef float floatx4 __attribute__((ext_vector_type(4)));

// ctrl layout: [0]=nf (count route==0), [1]=u_cnt, [2]=nf snapshot, [3]=nf_pad,
//              [4]=cursor_fake, [5]=cursor_real
__device__ inline u16 f2bf(float f) {
    u32 u = __builtin_bit_cast(u32, f);
    u32 r = (u + 0x7fffu + ((u >> 16) & 1u)) >> 16;
    return (u16)r;
}
__device__ inline float bf2f(u16 h) {
    return __builtin_bit_cast(float, ((u32)h) << 16);
}
__device__ inline void bf2x2(u32 p, float& lo, float& hi) {
    lo = __builtin_bit_cast(float, p << 16);
    hi = __builtin_bit_cast(float, p & 0xffff0000u);
}

__device__ inline void lds16(const void* g, void* l) {
    __builtin_amdgcn_global_load_lds(
        (const __attribute__((address_space(1))) u32*)g,
        (__attribute__((address_space(3))) u32*)l, 16, 0, 0);
}

__global__ __launch_bounds__(256) void zero_misc(int* idx_all, int* u_idx, int* ctrl) {
    int t = blockIdx.x * 256 + threadIdx.x;
    if (t < IDX_CAP) idx_all[t] = 0;
    if (t < UCAP) u_idx[t] = 0;
    if (t < 8) ctrl[t] = 0;
}

// fp32 -> hi bf16 only (x path: lo computed later for flagged rows only)
__global__ __launch_bounds__(256) void split_xhi(const float* __restrict__ in,
                                                 u16* __restrict__ hi, int n4) {
    int i = blockIdx.x * 256 + threadIdx.x;
    if (i >= n4) return;
    float4 f = ((const float4*)in)[i];
    ((ushort4*)hi)[i] = make_ushort4(f2bf(f.x), f2bf(f.y), f2bf(f.z), f2bf(f.w));
}

// gathered lo-split for flagged rows only (~2k of 32768); run after ln_route
__global__ __launch_bounds__(256) void split_xlo(const float* __restrict__ x,
                                                 const int* __restrict__ u_idx,
                                                 const int* __restrict__ ctrl,
                                                 u16* __restrict__ xlo) {
    int u = ctrl[1]; if (u > UCAP) u = UCAP;
    int r = blockIdx.x;
    if (r >= u) return;
    int orig = u_idx[r];
    const float4* src = (const float4*)(x + (size_t)orig * DD);
    ushort4* dst = (ushort4*)(xlo + (size_t)r * DD);
    int i = threadIdx.x;
#pragma unroll
    for (int k = 0; k < 2; ++k, i += 256) {
        float4 f = src[i];
        u16 h0 = f2bf(f.x), h1 = f2bf(f.y), h2 = f2bf(f.z), h3 = f2bf(f.w);
        dst[i] = make_ushort4(f2bf(f.x - bf2f(h0)), f2bf(f.y - bf2f(h1)),
                              f2bf(f.z - bf2f(h2)), f2bf(f.w - bf2f(h3)));
    }
}

// all three W1 splits in one launch (blockIdx.y selects matrix)
__global__ __launch_bounds__(256) void split_w3(const float* __restrict__ w0,
                                                const float* __restrict__ w1,
                                                const float* __restrict__ w2,
                                                u16* h0, u16* l0p,
                                                u16* h1, u16* l1p,
                                                u16* h2, u16* l2p) {
    int i = blockIdx.x * 256 + threadIdx.x;
    int m = blockIdx.y;
    const float* in = (m == 0) ? w0 : (m == 1) ? w1 : w2;
    u16* hi = (m == 0) ? h0 : (m == 1) ? h1 : h2;
    u16* lo = (m == 0) ? l0p : (m == 1) ? l1p : l2p;
    float4 f = ((const float4*)in)[i];
    u16 a0 = f2bf(f.x), a1 = f2bf(f.y), a2 = f2bf(f.z), a3 = f2bf(f.w);
    u16 b0 = f2bf(f.x - bf2f(a0)), b1 = f2bf(f.y - bf2f(a1));
    u16 b2 = f2bf(f.z - bf2f(a2)), b3 = f2bf(f.w - bf2f(a3));
    ((ushort4*)hi)[i] = make_ushort4(a0, a1, a2, a3);
    ((ushort4*)lo)[i] = make_ushort4(b0, b1, b2, b3);
}

// ---------------------------------------------------------------------------
// 256x256 bf16 GEMM, issue-early / wait-late pipeline:
// at the top of tile t: barrier (buf[other] readers done) -> burst-issue all
// 8 of tile t+1's global_load_lds -> vmcnt(8) (tile t's 8, issued one full
// tile ago, have landed) -> barrier -> compute 4 phases (no intra barriers;
// compiler manages lgkmcnt). Every load gets a full tile (~2500 cyc) of
// slack; vmcnt never drains below 8 in the main loop; 2 barriers/tile.
// BK=64, 512 thr = 8 waves (2M x 4N), per-wave 128x64 (acc[8][4]).
// LDS 128 KB: 2 buffers x (A 32K | B 32K), XOR-quad swizzle carried on the
// GLOBAL address (LDS dest wave-linear); frag ds_read_b128 conflict-free.
template <int IDX, int DUAL>
__global__ __launch_bounds__(512, 2) void gemm256(const u16* __restrict__ A,
                                                  const u16* __restrict__ B1,
                                                  const u16* __restrict__ B2,
                                                  u16* __restrict__ C,
                                                  const int* __restrict__ ridx,
                                                  const int* __restrict__ ctrl) {
    // T1: bijective XCD swizzle (nwg = 1024 or 1032, both divisible by 8)
    const int nwg = (int)(gridDim.x * gridDim.y);
    const int wg0 = (int)(blockIdx.y * gridDim.x + blockIdx.x);
    const int chunk = nwg >> 3;
    const int swz = (wg0 & 7) * chunk + (wg0 >> 3);
    const size_t bm = (size_t)(swz >> 3) * 256;   // gridDim.x == 8
    const size_t bn = (size_t)(swz & 7) * 256;

    const u16* Bp = B1;
    if (DUAL) {
        int nf_pad = ctrl[3];
        int limit = nf_pad + (BD - ctrl[2]);       // nf_pad + nr
        if ((int)bm >= limit) return;
        if ((int)bm >= nf_pad) Bp = B2;
    }

    __shared__ alignas(16) u16 smem[65536];        // 128 KB, 2 x (A 32K | B 32K)
    const int tid = threadIdx.x;
    const int lane = tid & 63;
    const int wave = tid >> 6;
    const int wr = wave >> 2, wc = wave & 3;       // 2M x 4N waves
    const int m16 = lane & 15, q4 = lane >> 4;

    const int srow = tid >> 3;                     // 0..63 (row within quarter)
    const int kq = ((tid & 7) ^ (srow & 7)) * 8;   // global col offset (elems)
    const int tid8 = tid * 8;                      // LDS u16 offset within quad-block
    size_t aOff[4], bOff[4];
#pragma unroll
    for (int s = 0; s < 4; ++s) {
        int row = s * 64 + srow;
        int g = IDX ? ridx[bm + row] : (int)(bm + row);
        aOff[s] = (size_t)g * DD + kq;
        bOff[s] = (size_t)(bn + row) * DD + kq;
    }

    const int slot0 = ((q4) ^ (m16 & 7)) * 8;
    const int slot1 = ((4 + q4) ^ (m16 & 7)) * 8;
    const int aFr = (wr * 128 + m16) * 64;
    const int bFr = 16384 + (wc * 64 + m16) * 64;

    floatx4 acc[8][4] = {};

    // A first (HBM, longest latency), then B (mostly L2-resident)
#define STAGE_TILE(DB, K0)                                              \
    lds16(A + aOff[0] + (K0), &smem[(DB) + 0 * 4096 + tid8]);           \
    lds16(A + aOff[1] + (K0), &smem[(DB) + 1 * 4096 + tid8]);           \
    lds16(A + aOff[2] + (K0), &smem[(DB) + 2 * 4096 + tid8]);           \
    lds16(A + aOff[3] + (K0), &smem[(DB) + 3 * 4096 + tid8]);           \
    lds16(Bp + bOff[0] + (K0), &smem[(DB) + 16384 + 0 * 4096 + tid8]);  \
    lds16(Bp + bOff[1] + (K0), &smem[(DB) + 16384 + 1 * 4096 + tid8]);  \
    lds16(Bp + bOff[2] + (K0), &smem[(DB) + 16384 + 2 * 4096 + tid8]);  \
    lds16(Bp + bOff[3] + (K0), &smem[(DB) + 16384 + 3 * 4096 + tid8]);

    // prologue: issue tile 0 into buffer 0
    STAGE_TILE(0, 0)

    int base = 0;
    const int NT = DD / 64;                        // 32 K-tiles
    for (int t = 0; t < NT; ++t) {
        const int nbase = base ^ 32768;
        __builtin_amdgcn_s_barrier();              // buf[nbase] readers done
        if (t + 1 < NT) {
            STAGE_TILE(nbase, (t + 1) * 64)
            asm volatile("s_waitcnt vmcnt(8)" ::: "memory");   // tile t landed
        } else {
            asm volatile("s_waitcnt vmcnt(0)" ::: "memory");
        }
        __builtin_amdgcn_s_barrier();              // all waves' tile-t data in LDS
        __builtin_amdgcn_sched_barrier(0);

        // compute tile t: B frags once, A frags per phase; compiler lgkmcnt
        bf16x8 bfr[2][4];
#pragma unroll
        for (int j = 0; j < 4; ++j) {
            bfr[0][j] = *(const bf16x8*)&smem[base + bFr + j * 1024 + slot0];
            bfr[1][j] = *(const bf16x8*)&smem[base + bFr + j * 1024 + slot1];
        }
#pragma unroll
        for (int p = 0; p < 4; ++p) {
            bf16x8 a0k0 = *(const bf16x8*)&smem[base + aFr + (2 * p) * 1024 + slot0];
            bf16x8 a0k1 = *(const bf16x8*)&smem[base + aFr + (2 * p) * 1024 + slot1];
            bf16x8 a1k0 = *(const bf16x8*)&smem[base + aFr + (2 * p + 1) * 1024 + slot0];
            bf16x8 a1k1 = *(const bf16x8*)&smem[base + aFr + (2 * p + 1) * 1024 + slot1];
            __builtin_amdgcn_s_setprio(1);
#pragma unroll
            for (int j = 0; j < 4; ++j) {
                acc[2 * p][j]     = __builtin_amdgcn_mfma_f32_16x16x32_bf16(a0k0, bfr[0][j], acc[2 * p][j], 0, 0, 0);
                acc[2 * p][j]     = __builtin_amdgcn_mfma_f32_16x16x32_bf16(a0k1, bfr[1][j], acc[2 * p][j], 0, 0, 0);
                acc[2 * p + 1][j] = __builtin_amdgcn_mfma_f32_16x16x32_bf16(a1k0, bfr[0][j], acc[2 * p + 1][j], 0, 0, 0);
                acc[2 * p + 1][j] = __builtin_amdgcn_mfma_f32_16x16x32_bf16(a1k1, bfr[1][j], acc[2 * p + 1][j], 0, 0, 0);
            }
            __builtin_amdgcn_s_setprio(0);
        }
        base = nbase;
    }
#undef STAGE_TILE

    // C/D layout (m89-verified): col = lane&15, row = (lane>>4)*4 + reg
#pragma unroll
    for (int i = 0; i < 8; ++i) {
#pragma unroll
        for (int r = 0; r < 4; ++r) {
            size_t grow = bm + wr * 128 + i * 16 + q4 * 4 + r;
            u16* crow = C + grow * DD + bn + wc * 64 + m16;
#pragma unroll
            for (int j = 0; j < 4; ++j) crow[j * 16] = f2bf(acc[i][j][r]);
        }
    }
}

// ---------------------------------------------------------------------------
// Split-precision GEMM (3-chain hi*hi+hi*lo+lo*hi), BK=32, fp32 out.
// Same issue-early/wait-late pipeline as gemm256 (double-buffered 64 KB LDS,
// burst-issue next K-step, vmcnt(8), 2 barriers/step). Ahi rows gathered via
// ridx (orig ids); Alo is COMPACT (row r = gathered position, from split_xlo).
__global__ __launch_bounds__(256) void gemm_split(const u16* __restrict__ Ahi,
                                                  const u16* __restrict__ Alo,
                                                  const u16* __restrict__ Bhi,
                                                  const u16* __restrict__ Blo,
                                                  float* __restrict__ C,
                                                  const int* __restrict__ ridx,
                                                  const int* __restrict__ ctrl) {
    const int tid = threadIdx.x;
    const size_t bm = (size_t)blockIdx.y * 128;
    const size_t bn = (size_t)blockIdx.x * 128;

    int u = ctrl[1]; if (u > UCAP) u = UCAP;
    if ((int)bm >= u) return;

    __shared__ alignas(16) u16 smem[2 * 16384];    // 64 KB: 2 x (Ahi|Bhi|Alo|Blo)
    const int lane = tid & 63;
    const int wave = tid >> 6;
    const int wm = (wave >> 1) * 64, wn = (wave & 1) * 64;
    const int m16 = lane & 15, q = lane >> 4;
    const int swzf = (q ^ ((m16 >> 1) & 3)) * 8;

    int aRow[2], gRow[2], kqv[2];
    size_t bOff[2];
#pragma unroll
    for (int s = 0; s < 2; ++s) {
        int e = s * 256 + tid;
        int row = e >> 2;
        int c = e & 3;
        kqv[s] = (c ^ ((row >> 1) & 3)) * 8;
        aRow[s] = ridx[bm + row];                  // orig row (full x_hi)
        gRow[s] = (int)bm + row;                   // gathered row (compact x_lo)
        bOff[s] = (size_t)(bn + row) * DD;
    }

    floatx4 acc[4][4] = {};

#define SPLIT_STAGE(DB, K0)                                                       \
    lds16(Ahi + (size_t)aRow[0] * DD + (K0) + kqv[0], &smem[(DB) + tid * 8]);     \
    lds16(Ahi + (size_t)aRow[1] * DD + (K0) + kqv[1], &smem[(DB) + 2048 + tid * 8]); \
    lds16(Bhi + bOff[0] + (K0) + kqv[0], &smem[(DB) + 4096 + tid * 8]);           \
    lds16(Bhi + bOff[1] + (K0) + kqv[1], &smem[(DB) + 6144 + tid * 8]);           \
    lds16(Alo + (size_t)gRow[0] * DD + (K0) + kqv[0], &smem[(DB) + 8192 + tid * 8]); \
    lds16(Alo + (size_t)gRow[1] * DD + (K0) + kqv[1], &smem[(DB) + 10240 + tid * 8]); \
    lds16(Blo + bOff[0] + (K0) + kqv[0], &smem[(DB) + 12288 + tid * 8]);          \
    lds16(Blo + bOff[1] + (K0) + kqv[1], &smem[(DB) + 14336 + tid * 8]);

    SPLIT_STAGE(0, 0)
    int base = 0;
    const int NTS = DD / 32;                       // 64 K-steps
    for (int t = 0; t < NTS; ++t) {
        const int nbase = base ^ 16384;
        __builtin_amdgcn_s_barrier();
        if (t + 1 < NTS) {
            SPLIT_STAGE(nbase, (t + 1) * 32)
            asm volatile("s_waitcnt vmcnt(8)" ::: "memory");
        } else {
            asm volatile("s_waitcnt vmcnt(0)" ::: "memory");
        }
        __builtin_amdgcn_s_barrier();
        __builtin_amdgcn_sched_barrier(0);

        bf16x8 ah[4], bh[4], al[4], bl[4];
#pragma unroll
        for (int i = 0; i < 4; ++i) {
            ah[i] = *(const bf16x8*)&smem[base + (wm + i * 16 + m16) * 32 + swzf];
            bh[i] = *(const bf16x8*)&smem[base + 4096 + (wn + i * 16 + m16) * 32 + swzf];
            al[i] = *(const bf16x8*)&smem[base + 8192 + (wm + i * 16 + m16) * 32 + swzf];
            bl[i] = *(const bf16x8*)&smem[base + 12288 + (wn + i * 16 + m16) * 32 + swzf];
        }
        __builtin_amdgcn_s_setprio(1);
#pragma unroll
        for (int i = 0; i < 4; ++i)
#pragma unroll
            for (int j = 0; j < 4; ++j) {
                acc[i][j] = __builtin_amdgcn_mfma_f32_16x16x32_bf16(ah[i], bh[j], acc[i][j], 0, 0, 0);
                acc[i][j] = __builtin_amdgcn_mfma_f32_16x16x32_bf16(ah[i], bl[j], acc[i][j], 0, 0, 0);
                acc[i][j] = __builtin_amdgcn_mfma_f32_16x16x32_bf16(al[i], bh[j], acc[i][j], 0, 0, 0);
            }
        __builtin_amdgcn_s_setprio(0);
        base = nbase;
    }
#undef SPLIT_STAGE

#pragma unroll
    for (int i = 0; i < 4; ++i)
#pragma unroll
        for (int r = 0; r < 4; ++r) {
            size_t grow = bm + wm + i * 16 + q * 4 + r;
            float* crow = C + grow * DD + bn + wn + m16;
#pragma unroll
            for (int j = 0; j < 4; ++j) crow[j * 16] = acc[i][j][r];
        }
}

// ---------------------------------------------------------------------------
// LDS param staging: sp = [b1 | g | be | W2row0 | W2row1], 5*2048 floats = 40KB.
__device__ inline void stage_params(float* __restrict__ sp,
                                    const float* __restrict__ b1,
                                    const float* __restrict__ g,
                                    const float* __restrict__ be,
                                    const float* __restrict__ W2, int tid) {
#pragma unroll
    for (int k = 0; k < 2; ++k) {
        int idx = (k * 256 + tid) * 4;             // 0..2047
        *(float4*)&sp[idx]          = *(const float4*)&b1[idx];
        *(float4*)&sp[2048 + idx]   = *(const float4*)&g[idx];
        *(float4*)&sp[4096 + idx]   = *(const float4*)&be[idx];
        *(float4*)&sp[6144 + idx]   = *(const float4*)&W2[idx];
        *(float4*)&sp[8192 + idx]   = *(const float4*)&W2[2048 + idx];
    }
}

// ---------------------------------------------------------------------------
// One row per wave. h row held in 16 VGPRs (4 x uint4, cols c*512 + lane*8);
// conversion recomputed in pass 2 -> no v[32] array, no reloads, no spills.
// Params from LDS (ds_read_b128, conflict-free: 16 B/lane stride).
__device__ inline void ln_row(const u16* __restrict__ hr,
                              const float* __restrict__ sp,
                              int lane, float b20, float b21,
                              float& L0, float& L1) {
    const int cb = lane * 8;
    uint4 h0 = *(const uint4*)(hr + 0 * 512 + cb);
    uint4 h1 = *(const uint4*)(hr + 1 * 512 + cb);
    uint4 h2 = *(const uint4*)(hr + 2 * 512 + cb);
    uint4 h3 = *(const uint4*)(hr + 3 * 512 + cb);

    float sum = 0.f, sumsq = 0.f;
#define LN_STATS(HV, C)                                                        \
    {                                                                          \
        int col = (C) * 512 + cb;                                              \
        float4 b0 = *(const float4*)(sp + col);                                \
        float4 b4 = *(const float4*)(sp + col + 4);                            \
        float f0, f1, f2, f3, f4, f5, f6, f7;                                  \
        bf2x2(HV.x, f0, f1); bf2x2(HV.y, f2, f3);                              \
        bf2x2(HV.z, f4, f5); bf2x2(HV.w, f6, f7);                              \
        f0 += b0.x; f1 += b0.y; f2 += b0.z; f3 += b0.w;                        \
        f4 += b4.x; f5 += b4.y; f6 += b4.z; f7 += b4.w;                        \
        sum += ((f0 + f1) + (f2 + f3)) + ((f4 + f5) + (f6 + f7));              \
        sumsq += ((f0 * f0 + f1 * f1) + (f2 * f2 + f3 * f3)) +                 \
                 ((f4 * f4 + f5 * f5) + (f6 * f6 + f7 * f7));                  \
    }
    LN_STATS(h0, 0) LN_STATS(h1, 1) LN_STATS(h2, 2) LN_STATS(h3, 3)
#undef LN_STATS
#pragma unroll
    for (int off = 32; off > 0; off >>= 1) {
        sum += __shfl_xor(sum, off);
        sumsq += __shfl_xor(sumsq, off);
    }
    const float mu = sum * (1.f / 2048.f);
    const float var = sumsq * (1.f / 2048.f) - mu * mu;
    const float rstd = rsqrtf(var + LN_EPS);

    float l0 = 0.f, l1 = 0.f;
#define LN_HEAD(HV, C)                                                         \
    {                                                                          \
        int col = (C) * 512 + cb;                                              \
        float4 b0 = *(const float4*)(sp + col);                                \
        float4 b4 = *(const float4*)(sp + col + 4);                            \
        float4 g0 = *(const float4*)(sp + 2048 + col);                         \
        float4 g4 = *(const float4*)(sp + 2048 + col + 4);                     \
        float4 e0 = *(const float4*)(sp + 4096 + col);                         \
        float4 e4 = *(const float4*)(sp + 4096 + col + 4);                     \
        float4 w00 = *(const float4*)(sp + 6144 + col);                        \
        float4 w04 = *(const float4*)(sp + 6144 + col + 4);                    \
        float4 w10 = *(const float4*)(sp + 8192 + col);                        \
        float4 w14 = *(const float4*)(sp + 8192 + col + 4);                    \
        float f0, f1, f2, f3, f4, f5, f6, f7, hn;                              \
        bf2x2(HV.x, f0, f1); bf2x2(HV.y, f2, f3);                              \
        bf2x2(HV.z, f4, f5); bf2x2(HV.w, f6, f7);                              \
        hn = fmaxf(((f0 + b0.x) - mu) * rstd * g0.x + e0.x, 0.f); l0 += hn * w00.x; l1 += hn * w10.x; \
        hn = fmaxf(((f1 + b0.y) - mu) * rstd * g0.y + e0.y, 0.f); l0 += hn * w00.y; l1 += hn * w10.y; \
        hn = fmaxf(((f2 + b0.z) - mu) * rstd * g0.z + e0.z, 0.f); l0 += hn * w00.z; l1 += hn * w10.z; \
        hn = fmaxf(((f3 + b0.w) - mu) * rstd * g0.w + e0.w, 0.f); l0 += hn * w00.w; l1 += hn * w10.w; \
        hn = fmaxf(((f4 + b4.x) - mu) * rstd * g4.x + e4.x, 0.f); l0 += hn * w04.x; l1 += hn * w14.x; \
        hn = fmaxf(((f5 + b4.y) - mu) * rstd * g4.y + e4.y, 0.f); l0 += hn * w04.y; l1 += hn * w14.y; \
        hn = fmaxf(((f6 + b4.z) - mu) * rstd * g4.z + e4.z, 0.f); l0 += hn * w04.z; l1 += hn * w14.z; \
        hn = fmaxf(((f7 + b4.w) - mu) * rstd * g4.w + e4.w, 0.f); l0 += hn * w04.w; l1 += hn * w14.w; \
    }
    LN_HEAD(h0, 0) LN_HEAD(h1, 1) LN_HEAD(h2, 2) LN_HEAD(h3, 3)
#undef LN_HEAD
#pragma unroll
    for (int off = 32; off > 0; off >>= 1) {
        l0 += __shfl_xor(l0, off);
        l1 += __shfl_xor(l1, off);
    }
    L0 = l0 + b20;
    L1 = l1 + b21;
}

// fp32-h LN core (fixup path only, few rows)
__device__ inline void ln_core(const float* __restrict__ hr,
                               const float* __restrict__ b1,
                               const float* __restrict__ g,
                               const float* __restrict__ be,
                               const float* __restrict__ W2,
                               const float* __restrict__ b2,
                               int lane, float& L0, float& L1) {
    float v[32];
    float sum = 0.f, sumsq = 0.f;
#pragma unroll
    for (int i = 0; i < 8; ++i) {
        int col = i * 256 + lane * 4;
        float4 t = *(const float4*)(hr + col);
        float4 bb = *(const float4*)(b1 + col);
        t.x += bb.x; t.y += bb.y; t.z += bb.z; t.w += bb.w;
        v[i * 4 + 0] = t.x; v[i * 4 + 1] = t.y; v[i * 4 + 2] = t.z; v[i * 4 + 3] = t.w;
        sum += t.x + t.y + t.z + t.w;
        sumsq += t.x * t.x + t.y * t.y + t.z * t.z + t.w * t.w;
    }
#pragma unroll
    for (int off = 32; off > 0; off >>= 1) {
        sum += __shfl_xor(sum, off);
        sumsq += __shfl_xor(sumsq, off);
    }
    const float mu = sum * (1.f / 2048.f);
    const float var = sumsq * (1.f / 2048.f) - mu * mu;
    const float rstd = rsqrtf(var + LN_EPS);

    float l0 = 0.f, l1 = 0.f;
#pragma unroll
    for (int i = 0; i < 8; ++i) {
        int col = i * 256 + lane * 4;
        float4 gg = *(const float4*)(g + col);
        float4 bbe = *(const float4*)(be + col);
        float4 w0 = *(const float4*)(W2 + col);
        float4 w1 = *(const float4*)(W2 + DD + col);
        float hn;
        hn = fmaxf((v[i * 4 + 0] - mu) * rstd * gg.x + bbe.x, 0.f); l0 += hn * w0.x; l1 += hn * w1.x;
        hn = fmaxf((v[i * 4 + 1] - mu) * rstd * gg.y + bbe.y, 0.f); l0 += hn * w0.y; l1 += hn * w1.y;
        hn = fmaxf((v[i * 4 + 2] - mu) * rstd * gg.z + bbe.z, 0.f); l0 += hn * w0.z; l1 += hn * w1.z;
        hn = fmaxf((v[i * 4 + 3] - mu) * rstd * gg.w + bbe.w, 0.f); l0 += hn * w0.w; l1 += hn * w1.w;
    }
#pragma unroll
    for (int off = 32; off > 0; off >>= 1) {
        l0 += __shfl_xor(l0, off);
        l1 += __shfl_xor(l1, off);
    }
    L0 = l0 + b2[0];
    L1 = l1 + b2[1];
}

// Branch-1: route = argmax, count nf (block-aggregated), flag near-ties.
// Non-persistent: 8192 blocks x 4 waves, one row per wave (max TLP).
__global__ __launch_bounds__(256) void ln_route(const u16* __restrict__ h,
                                                const float* __restrict__ b1,
                                                const float* __restrict__ g,
                                                const float* __restrict__ be,
                                                const float* __restrict__ W2,
                                                const float* __restrict__ b2,
                                                int* __restrict__ route,
                                                int* __restrict__ ctrl,
                                                int* __restrict__ u_idx) {
    __shared__ float sp[5 * 2048];
    __shared__ int blk_nf;
    const int tid = threadIdx.x;
    if (tid == 0) blk_nf = 0;
    stage_params(sp, b1, g, be, W2, tid);
    __syncthreads();
    const int wave = tid >> 6, lane = tid & 63;
    const int r = blockIdx.x * 4 + wave;
    float l0, l1;
    ln_row(h + (size_t)r * DD, sp, lane, b2[0], b2[1], l0, l1);
    if (lane == 0) {
        int rt = (l0 >= l1) ? 0 : 1;
        route[r] = rt;
        if (rt == 0) atomicAdd(&blk_nf, 1);
        if (fabsf(l0 - l1) < MARGIN) {
            int p = atomicAdd(&ctrl[1], 1);
            if (p < UCAP) u_idx[p] = r;
        }
    }
    __syncthreads();
    if (tid == 0 && blk_nf) atomicAdd(&ctrl[0], blk_nf);
}

// Recheck flagged rows with split-precision h (fp32, gathered order).
__global__ __launch_bounds__(256) void ln_fixup(const float* __restrict__ h,
                                                const float* __restrict__ b1,
                                                const float* __restrict__ g,
                                                const float* __restrict__ be,
                                                const float* __restrict__ W2,
                                                const float* __restrict__ b2,
                                                int* __restrict__ route,
                                                int* __restrict__ ctrl,
                                                const int* __restrict__ u_idx) {
    const int wave = threadIdx.x >> 6, lane = threadIdx.x & 63;
    const int r = blockIdx.x * 4 + wave;
    int u = ctrl[1]; if (u > UCAP) u = UCAP;
    if (r >= u) return;
    const int orig = u_idx[r];
    float l0, l1;
    ln_core(h + (size_t)r * DD, b1, g, be, W2, b2, lane, l0, l1);
    if (lane == 0) {
        int rt = (l0 >= l1) ? 0 : 1;
        int old = route[orig];
        if (rt != old) {
            atomicAdd(&ctrl[0], rt == 0 ? 1 : -1);
            route[orig] = rt;
        }
    }
}

__global__ void init_ctrl(int* ctrl) {
    int nf = ctrl[0];
    ctrl[2] = nf;
    ctrl[3] = (nf + 255) & ~255;                   // 256-aligned (256-row GEMM tiles)
    ctrl[4] = 0;
    ctrl[5] = ctrl[3];
}

// Compact rows: fake segment at [0,nf), real segment at [nf_pad, nf_pad+nr).
__global__ __launch_bounds__(256) void compact(const int* __restrict__ route,
                                               int* __restrict__ ctrl,
                                               int* __restrict__ idx_all) {
    const int row = blockIdx.x * 256 + threadIdx.x;
    const int lane = threadIdx.x & 63;
    const bool isf = (route[row] == 0);
    unsigned long long m = __ballot(isf);
    int nfw = __popcll(m);
    int baseF = 0, baseR = 0;
    if (lane == 0) {
        baseF = atomicAdd(&ctrl[4], nfw);
        baseR = atomicAdd(&ctrl[5], 64 - nfw);
    }
    baseF = __shfl(baseF, 0);
    baseR = __shfl(baseR, 0);
    unsigned long long lt = (lane == 0) ? 0ull : ((~0ull) >> (64 - lane));
    int pre = __popcll(m & lt);
    int pos = isf ? (baseF + pre) : (baseR + (lane - pre));
    idx_all[pos] = row;
}

// Final pass over combined gathered bf16 h. One row per wave, non-persistent.
// Segment per BLOCK: real segment starts 256-aligned (nf_pad), blocks are
// 4-row aligned -> no block ever straddles fake|real. Gap blocks return.
__global__ __launch_bounds__(256) void ln_final(const u16* __restrict__ h,
                                                const float* __restrict__ b1f, const float* __restrict__ gf,
                                                const float* __restrict__ bef, const float* __restrict__ W2f,
                                                const float* __restrict__ b2f,
                                                const float* __restrict__ b1r, const float* __restrict__ gr,
                                                const float* __restrict__ ber, const float* __restrict__ W2r,
                                                const float* __restrict__ b2r,
                                                const int* __restrict__ ctrl,
                                                const int* __restrict__ idx_all,
                                                float* __restrict__ out) {
    const int nf = ctrl[2], nf_pad = ctrl[3];
    const int limit = nf_pad + (BD - nf);
    const int base = blockIdx.x * 4;
    bool fake;
    if (base < nf) fake = true;
    else if (base >= nf_pad && base < limit) fake = false;
    else return;                                   // gap / beyond-limit blocks (uniform)

    __shared__ float sp[5 * 2048];
    const int tid = threadIdx.x;
    stage_params(sp, fake ? b1f : b1r, fake ? gf : gr, fake ? bef : ber,
                 fake ? W2f : W2r, tid);
    __syncthreads();
    const int wave = tid >> 6, lane = tid & 63;
    const int r = base + wave;
    if (fake ? (r < nf) : (r < limit)) {
        const float* b2 = fake ? b2f : b2r;
        float l0, l1;
        ln_row(h + (size_t)r * DD, sp, lane, b2[0], b2[1], l0, l1);
        if (lane == 0) {
            int orig = idx_all[r];
            out[(size_t)orig * 2 + 0] = l0;
            out[(size_t)orig * 2 + 1] = l1;
        }
    }
}

extern "C" void kernel_launch(void* const* d_in, const int* in_sizes, int n_in,
                              void* d_out, int out_size, void* d_ws, size_t ws_size,
                              hipStream_t stream) {
    const float* x = (const float*)d_in[0];
    const float* W1[3] = {(const float*)d_in[1], (const float*)d_in[7], (const float*)d_in[13]};
    const float* b1[3] = {(const float*)d_in[2], (const float*)d_in[8], (const float*)d_in[14]};
    const float* lg[3] = {(const float*)d_in[3], (const float*)d_in[9], (const float*)d_in[15]};
    const float* lb[3] = {(const float*)d_in[4], (const float*)d_in[10], (const float*)d_in[16]};
    const float* W2[3] = {(const float*)d_in[5], (const float*)d_in[11], (const float*)d_in[17]};
    const float* b2[3] = {(const float*)d_in[6], (const float*)d_in[12], (const float*)d_in[18]};

    char* ws = (char*)d_ws;
    size_t off = 0;
    u16* x_hi = (u16*)(ws + off); off += (size_t)BD * DD * 2;        // 134 MB
    u16* x_lo = (u16*)(ws + off); off += (size_t)UCAP * DD * 2;      // 32 MB (compact, flagged rows)
    u16* w_hi[3];
    u16* w_lo[3];
    for (int i = 0; i < 3; ++i) { w_hi[i] = (u16*)(ws + off); off += (size_t)DD * DD * 2; }
    for (int i = 0; i < 3; ++i) { w_lo[i] = (u16*)(ws + off); off += (size_t)DD * DD * 2; }
    u16* h16 = (u16*)(ws + off); off += (size_t)IDX_CAP * DD * 2;    // 136 MB
    float* hfix = (float*)(ws + off); off += (size_t)UCAP * DD * 4;  // 67 MB
    int* route = (int*)(ws + off); off += (size_t)BD * 4;
    int* idx_all = (int*)(ws + off); off += (size_t)IDX_CAP * 4;
    int* u_idx = (int*)(ws + off); off += (size_t)UCAP * 4;
    int* ctrl = (int*)(ws + off); off += 64;

    // 0) zero control/index buffers (ws is poisoned each replay)
    zero_misc<<<(IDX_CAP + 255) / 256, 256, 0, stream>>>(idx_all, u_idx, ctrl);

    // 1) precision splits (x hi-only; all three W1 in one launch)
    split_xhi<<<(BD * DD / 4) / 256, 256, 0, stream>>>(x, x_hi, BD * DD / 4);
    split_w3<<<dim3((DD * DD / 4) / 256, 3), 256, 0, stream>>>(
        W1[0], W1[1], W1[2], w_hi[0], w_lo[0], w_hi[1], w_lo[1], w_hi[2], w_lo[2]);

    // 2) branch 1 in bf16 (256² issue-early pipeline); route + near-tie flags
    gemm256<0, 0><<<dim3(DD / 256, BD / 256), 512, 0, stream>>>(
        x_hi, w_hi[0], nullptr, h16, nullptr, nullptr);
    ln_route<<<BD / 4, 256, 0, stream>>>(h16, b1[0], lg[0], lb[0], W2[0], b2[0],
                                         route, ctrl, u_idx);

    // 3) lo-split for flagged rows only, then split-precision recheck
    split_xlo<<<UCAP, 256, 0, stream>>>(x, u_idx, ctrl, x_lo);
    gemm_split<<<dim3(DD / 128, UCAP / 128), 256, 0, stream>>>(
        x_hi, x_lo, w_hi[0], w_lo[0], hfix, u_idx, ctrl);
    ln_fixup<<<UCAP / 4, 256, 0, stream>>>(hfix, b1[0], lg[0], lb[0], W2[0], b2[0],
                                           route, ctrl, u_idx);

    // 4) compact rows into fake|real segments (256-padded boundary)
    init_ctrl<<<1, 1, 0, stream>>>(ctrl);
    compact<<<BD / 256, 256, 0, stream>>>(route, ctrl, idx_all);

    // 5) one combined gathered GEMM over both segments (per-row-block B select)
    gemm256<1, 1><<<dim3(DD / 256, BD / 256 + 1), 512, 0, stream>>>(
        x_hi, w_hi[1], w_hi[2], h16, idx_all, ctrl);

    // 6) final LN+head, scatter to out by original row
    ln_final<<<IDX_CAP / 4, 256, 0, stream>>>(
        h16, b1[1], lg[1], lb[1], W2[1], b2[1],
        b1[2], lg[2], lb[2], W2[2], b2[2],
        ctrl, idx_all, (float*)d_out);
}

// Round 7
// 1098.383 us; speedup vs baseline: 1.1287x; 1.1287x over previous
//
#include <hip/hip_runtime.h>

#define BD 32768
#define DD 2048
#define LN_EPS 1e-5f
#define MARGIN 0.03f
#define UCAP 8192          // max rows re-checked at split precision (expected ~2k)
#define IDX_CAP 33280      // 32768 + 2*256 padding (256-tile segments)

typedef unsigned short u16;
typedef unsigned int u32;
typedef __bf16 bf16x8 __attribute__((ext_vector_type(8)));
typedef float floatx4 __attribute__((ext_vector_type(4)));

// ctrl layout: [0]=nf (count route==0), [1]=u_cnt, [2]=nf snapshot, [3]=nf_pad,
//              [4]=cursor_fake, [5]=cursor_real
__device__ inline u16 f2bf(float f) {
    u32 u = __builtin_bit_cast(u32, f);
    u32 r = (u + 0x7fffu + ((u >> 16) & 1u)) >> 16;
    return (u16)r;
}
__device__ inline float bf2f(u16 h) {
    return __builtin_bit_cast(float, ((u32)h) << 16);
}
__device__ inline void bf2x2(u32 p, float& lo, float& hi) {
    lo = __builtin_bit_cast(float, p << 16);
    hi = __builtin_bit_cast(float, p & 0xffff0000u);
}

__device__ inline void lds16(const void* g, void* l) {
    __builtin_amdgcn_global_load_lds(
        (const __attribute__((address_space(1))) u32*)g,
        (__attribute__((address_space(3))) u32*)l, 16, 0, 0);
}

__global__ __launch_bounds__(256) void zero_misc(int* idx_all, int* u_idx, int* ctrl) {
    int t = blockIdx.x * 256 + threadIdx.x;
    if (t < IDX_CAP) idx_all[t] = 0;
    if (t < UCAP) u_idx[t] = 0;
    if (t < 8) ctrl[t] = 0;
}

// fp32 -> hi bf16 only (x path: lo computed later for flagged rows only)
__global__ __launch_bounds__(256) void split_xhi(const float* __restrict__ in,
                                                 u16* __restrict__ hi, int n4) {
    int i = blockIdx.x * 256 + threadIdx.x;
    if (i >= n4) return;
    float4 f = ((const float4*)in)[i];
    ((ushort4*)hi)[i] = make_ushort4(f2bf(f.x), f2bf(f.y), f2bf(f.z), f2bf(f.w));
}

// gathered lo-split for flagged rows only (~2k of 32768); run after ln_route
__global__ __launch_bounds__(256) void split_xlo(const float* __restrict__ x,
                                                 const int* __restrict__ u_idx,
                                                 const int* __restrict__ ctrl,
                                                 u16* __restrict__ xlo) {
    int u = ctrl[1]; if (u > UCAP) u = UCAP;
    int r = blockIdx.x;
    if (r >= u) return;
    int orig = u_idx[r];
    const float4* src = (const float4*)(x + (size_t)orig * DD);
    ushort4* dst = (ushort4*)(xlo + (size_t)r * DD);
    int i = threadIdx.x;
#pragma unroll
    for (int k = 0; k < 2; ++k, i += 256) {
        float4 f = src[i];
        u16 h0 = f2bf(f.x), h1 = f2bf(f.y), h2 = f2bf(f.z), h3 = f2bf(f.w);
        dst[i] = make_ushort4(f2bf(f.x - bf2f(h0)), f2bf(f.y - bf2f(h1)),
                              f2bf(f.z - bf2f(h2)), f2bf(f.w - bf2f(h3)));
    }
}

// all three W1 splits in one launch (blockIdx.y selects matrix)
__global__ __launch_bounds__(256) void split_w3(const float* __restrict__ w0,
                                                const float* __restrict__ w1,
                                                const float* __restrict__ w2,
                                                u16* h0, u16* l0p,
                                                u16* h1, u16* l1p,
                                                u16* h2, u16* l2p) {
    int i = blockIdx.x * 256 + threadIdx.x;
    int m = blockIdx.y;
    const float* in = (m == 0) ? w0 : (m == 1) ? w1 : w2;
    u16* hi = (m == 0) ? h0 : (m == 1) ? h1 : h2;
    u16* lo = (m == 0) ? l0p : (m == 1) ? l1p : l2p;
    float4 f = ((const float4*)in)[i];
    u16 a0 = f2bf(f.x), a1 = f2bf(f.y), a2 = f2bf(f.z), a3 = f2bf(f.w);
    u16 b0 = f2bf(f.x - bf2f(a0)), b1 = f2bf(f.y - bf2f(a1));
    u16 b2 = f2bf(f.z - bf2f(a2)), b3 = f2bf(f.w - bf2f(a3));
    ((ushort4*)hi)[i] = make_ushort4(a0, a1, a2, a3);
    ((ushort4*)lo)[i] = make_ushort4(b0, b1, b2, b3);
}

// ---------------------------------------------------------------------------
// 256x256 bf16 GEMM with COUNTED-vmcnt pipeline — EXACT round-4 schedule
// (best measured: 287 µs, MfmaUtil 42.7%). Per K-tile t, staging issues for
// tile t+1 interleaved with compute phases: p0:B01 p1:A02 p2:B23 p3:A13.
// Waits: before phase 2, vmcnt(6) (current tile's A q1,q3 = oldest 2 of 8);
// at tile boundary, vmcnt(2) (next tile's B+Aq0,q2 = oldest 6 of 8). Loads
// never drain to 0 in the main loop. 2 barriers per K-tile.
template <int IDX, int DUAL>
__global__ __launch_bounds__(512, 2) void gemm256(const u16* __restrict__ A,
                                                  const u16* __restrict__ B1,
                                                  const u16* __restrict__ B2,
                                                  u16* __restrict__ C,
                                                  const int* __restrict__ ridx,
                                                  const int* __restrict__ ctrl) {
    // T1: bijective XCD swizzle (nwg = 1024 or 1032, both divisible by 8)
    const int nwg = (int)(gridDim.x * gridDim.y);
    const int wg0 = (int)(blockIdx.y * gridDim.x + blockIdx.x);
    const int chunk = nwg >> 3;
    const int swz = (wg0 & 7) * chunk + (wg0 >> 3);
    const size_t bm = (size_t)(swz >> 3) * 256;   // gridDim.x == 8
    const size_t bn = (size_t)(swz & 7) * 256;

    const u16* Bp = B1;
    if (DUAL) {
        int nf_pad = ctrl[3];
        int limit = nf_pad + (BD - ctrl[2]);       // nf_pad + nr
        if ((int)bm >= limit) return;
        if ((int)bm >= nf_pad) Bp = B2;
    }

    __shared__ alignas(16) u16 smem[65536];        // 128 KB, 2 x (A 32K | B 32K)
    const int tid = threadIdx.x;
    const int lane = tid & 63;
    const int wave = tid >> 6;
    const int wr = wave >> 2, wc = wave & 3;       // 2M x 4N waves
    const int m16 = lane & 15, q4 = lane >> 4;

    const int srow = tid >> 3;                     // 0..63 (row within quarter)
    const int kq = ((tid & 7) ^ (srow & 7)) * 8;   // global col offset (elems)
    const int tid8 = tid * 8;                      // LDS u16 offset within quad-block
    size_t aOff[4], bOff[4];
#pragma unroll
    for (int s = 0; s < 4; ++s) {
        int row = s * 64 + srow;
        int g = IDX ? ridx[bm + row] : (int)(bm + row);
        aOff[s] = (size_t)g * DD + kq;
        bOff[s] = (size_t)(bn + row) * DD + kq;
    }

    const int slot0 = ((q4) ^ (m16 & 7)) * 8;
    const int slot1 = ((4 + q4) ^ (m16 & 7)) * 8;
    const int aFr = (wr * 128 + m16) * 64;
    const int bFr = 16384 + (wc * 64 + m16) * 64;

    floatx4 acc[8][4] = {};

    // prologue: stage K-tile 0 into buffer 0, same issue ORDER as steady state
    lds16(Bp + bOff[0], &smem[16384 + 0 * 4096 + tid8]);
    lds16(Bp + bOff[1], &smem[16384 + 1 * 4096 + tid8]);
    lds16(A + aOff[0], &smem[0 * 4096 + tid8]);
    lds16(A + aOff[2], &smem[2 * 4096 + tid8]);
    lds16(Bp + bOff[2], &smem[16384 + 2 * 4096 + tid8]);
    lds16(Bp + bOff[3], &smem[16384 + 3 * 4096 + tid8]);
    lds16(A + aOff[1], &smem[1 * 4096 + tid8]);
    lds16(A + aOff[3], &smem[3 * 4096 + tid8]);
    asm volatile("s_waitcnt vmcnt(2)" ::: "memory");   // B*, Aq0, Aq2 landed
    __builtin_amdgcn_s_barrier();
    __builtin_amdgcn_sched_barrier(0);

    int base = 0;
    const int NT = DD / 64;                        // 32 K-tiles
    for (int t = 0; t < NT - 1; ++t) {
        const int nbase = base ^ 32768;
        const int k0n = (t + 1) * 64;

        bf16x8 bfr[2][4];
#pragma unroll
        for (int j = 0; j < 4; ++j) {
            bfr[0][j] = *(const bf16x8*)&smem[base + bFr + j * 1024 + slot0];
            bfr[1][j] = *(const bf16x8*)&smem[base + bFr + j * 1024 + slot1];
        }

#pragma unroll
        for (int p = 0; p < 4; ++p) {
            if (p == 0) {
                lds16(Bp + bOff[0] + k0n, &smem[nbase + 16384 + 0 * 4096 + tid8]);
                lds16(Bp + bOff[1] + k0n, &smem[nbase + 16384 + 1 * 4096 + tid8]);
            } else if (p == 1) {
                lds16(A + aOff[0] + k0n, &smem[nbase + 0 * 4096 + tid8]);
                lds16(A + aOff[2] + k0n, &smem[nbase + 2 * 4096 + tid8]);
            } else if (p == 2) {
                lds16(Bp + bOff[2] + k0n, &smem[nbase + 16384 + 2 * 4096 + tid8]);
                lds16(Bp + bOff[3] + k0n, &smem[nbase + 16384 + 3 * 4096 + tid8]);
            } else {
                lds16(A + aOff[1] + k0n, &smem[nbase + 1 * 4096 + tid8]);
                lds16(A + aOff[3] + k0n, &smem[nbase + 3 * 4096 + tid8]);
            }
            if (p == 2) {
                // current tile's A q1,q3 are the oldest 2 of 8 outstanding
                asm volatile("s_waitcnt vmcnt(6)" ::: "memory");
                __builtin_amdgcn_s_barrier();
                __builtin_amdgcn_sched_barrier(0);
            }
            bf16x8 a0k0 = *(const bf16x8*)&smem[base + aFr + (2 * p) * 1024 + slot0];
            bf16x8 a0k1 = *(const bf16x8*)&smem[base + aFr + (2 * p) * 1024 + slot1];
            bf16x8 a1k0 = *(const bf16x8*)&smem[base + aFr + (2 * p + 1) * 1024 + slot0];
            bf16x8 a1k1 = *(const bf16x8*)&smem[base + aFr + (2 * p + 1) * 1024 + slot1];
            __builtin_amdgcn_s_setprio(1);
#pragma unroll
            for (int j = 0; j < 4; ++j) {
                acc[2 * p][j]     = __builtin_amdgcn_mfma_f32_16x16x32_bf16(a0k0, bfr[0][j], acc[2 * p][j], 0, 0, 0);
                acc[2 * p][j]     = __builtin_amdgcn_mfma_f32_16x16x32_bf16(a0k1, bfr[1][j], acc[2 * p][j], 0, 0, 0);
                acc[2 * p + 1][j] = __builtin_amdgcn_mfma_f32_16x16x32_bf16(a1k0, bfr[0][j], acc[2 * p + 1][j], 0, 0, 0);
                acc[2 * p + 1][j] = __builtin_amdgcn_mfma_f32_16x16x32_bf16(a1k1, bfr[1][j], acc[2 * p + 1][j], 0, 0, 0);
            }
            __builtin_amdgcn_s_setprio(0);
        }

        // boundary: next tile's B(all)+Aq0,Aq2 = oldest 6 of 8; A q1,q3 lag
        asm volatile("s_waitcnt vmcnt(2)" ::: "memory");
        __builtin_amdgcn_s_barrier();
        __builtin_amdgcn_sched_barrier(0);
        base = nbase;
    }

    // epilogue tile NT-1: no staging; only A q1,q3 outstanding at phase 2
    {
        bf16x8 bfr[2][4];
#pragma unroll
        for (int j = 0; j < 4; ++j) {
            bfr[0][j] = *(const bf16x8*)&smem[base + bFr + j * 1024 + slot0];
            bfr[1][j] = *(const bf16x8*)&smem[base + bFr + j * 1024 + slot1];
        }
#pragma unroll
        for (int p = 0; p < 4; ++p) {
            if (p == 2) {
                asm volatile("s_waitcnt vmcnt(0)" ::: "memory");
                __builtin_amdgcn_s_barrier();
                __builtin_amdgcn_sched_barrier(0);
            }
            bf16x8 a0k0 = *(const bf16x8*)&smem[base + aFr + (2 * p) * 1024 + slot0];
            bf16x8 a0k1 = *(const bf16x8*)&smem[base + aFr + (2 * p) * 1024 + slot1];
            bf16x8 a1k0 = *(const bf16x8*)&smem[base + aFr + (2 * p + 1) * 1024 + slot0];
            bf16x8 a1k1 = *(const bf16x8*)&smem[base + aFr + (2 * p + 1) * 1024 + slot1];
            __builtin_amdgcn_s_setprio(1);
#pragma unroll
            for (int j = 0; j < 4; ++j) {
                acc[2 * p][j]     = __builtin_amdgcn_mfma_f32_16x16x32_bf16(a0k0, bfr[0][j], acc[2 * p][j], 0, 0, 0);
                acc[2 * p][j]     = __builtin_amdgcn_mfma_f32_16x16x32_bf16(a0k1, bfr[1][j], acc[2 * p][j], 0, 0, 0);
                acc[2 * p + 1][j] = __builtin_amdgcn_mfma_f32_16x16x32_bf16(a1k0, bfr[0][j], acc[2 * p + 1][j], 0, 0, 0);
                acc[2 * p + 1][j] = __builtin_amdgcn_mfma_f32_16x16x32_bf16(a1k1, bfr[1][j], acc[2 * p + 1][j], 0, 0, 0);
            }
            __builtin_amdgcn_s_setprio(0);
        }
    }

    // C/D layout (m89-verified): col = lane&15, row = (lane>>4)*4 + reg
#pragma unroll
    for (int i = 0; i < 8; ++i) {
#pragma unroll
        for (int r = 0; r < 4; ++r) {
            size_t grow = bm + wr * 128 + i * 16 + q4 * 4 + r;
            u16* crow = C + grow * DD + bn + wc * 64 + m16;
#pragma unroll
            for (int j = 0; j < 4; ++j) crow[j * 16] = f2bf(acc[i][j][r]);
        }
    }
}

// ---------------------------------------------------------------------------
// Split-precision GEMM (3-chain hi*hi+hi*lo+lo*hi), BK=32, fp32 out.
// Issue-early/wait-late pipeline (double-buffered 64 KB LDS). Ahi rows
// gathered via ridx (orig ids); Alo is COMPACT (row r = gathered position).
__global__ __launch_bounds__(256) void gemm_split(const u16* __restrict__ Ahi,
                                                  const u16* __restrict__ Alo,
                                                  const u16* __restrict__ Bhi,
                                                  const u16* __restrict__ Blo,
                                                  float* __restrict__ C,
                                                  const int* __restrict__ ridx,
                                                  const int* __restrict__ ctrl) {
    const int tid = threadIdx.x;
    const size_t bm = (size_t)blockIdx.y * 128;
    const size_t bn = (size_t)blockIdx.x * 128;

    int u = ctrl[1]; if (u > UCAP) u = UCAP;
    if ((int)bm >= u) return;

    __shared__ alignas(16) u16 smem[2 * 16384];    // 64 KB: 2 x (Ahi|Bhi|Alo|Blo)
    const int lane = tid & 63;
    const int wave = tid >> 6;
    const int wm = (wave >> 1) * 64, wn = (wave & 1) * 64;
    const int m16 = lane & 15, q = lane >> 4;
    const int swzf = (q ^ ((m16 >> 1) & 3)) * 8;

    int aRow[2], gRow[2], kqv[2];
    size_t bOff[2];
#pragma unroll
    for (int s = 0; s < 2; ++s) {
        int e = s * 256 + tid;
        int row = e >> 2;
        int c = e & 3;
        kqv[s] = (c ^ ((row >> 1) & 3)) * 8;
        aRow[s] = ridx[bm + row];                  // orig row (full x_hi)
        gRow[s] = (int)bm + row;                   // gathered row (compact x_lo)
        bOff[s] = (size_t)(bn + row) * DD;
    }

    floatx4 acc[4][4] = {};

#define SPLIT_STAGE(DB, K0)                                                       \
    lds16(Ahi + (size_t)aRow[0] * DD + (K0) + kqv[0], &smem[(DB) + tid * 8]);     \
    lds16(Ahi + (size_t)aRow[1] * DD + (K0) + kqv[1], &smem[(DB) + 2048 + tid * 8]); \
    lds16(Bhi + bOff[0] + (K0) + kqv[0], &smem[(DB) + 4096 + tid * 8]);           \
    lds16(Bhi + bOff[1] + (K0) + kqv[1], &smem[(DB) + 6144 + tid * 8]);           \
    lds16(Alo + (size_t)gRow[0] * DD + (K0) + kqv[0], &smem[(DB) + 8192 + tid * 8]); \
    lds16(Alo + (size_t)gRow[1] * DD + (K0) + kqv[1], &smem[(DB) + 10240 + tid * 8]); \
    lds16(Blo + bOff[0] + (K0) + kqv[0], &smem[(DB) + 12288 + tid * 8]);          \
    lds16(Blo + bOff[1] + (K0) + kqv[1], &smem[(DB) + 14336 + tid * 8]);

    SPLIT_STAGE(0, 0)
    int base = 0;
    const int NTS = DD / 32;                       // 64 K-steps
    for (int t = 0; t < NTS; ++t) {
        const int nbase = base ^ 16384;
        __builtin_amdgcn_s_barrier();
        if (t + 1 < NTS) {
            SPLIT_STAGE(nbase, (t + 1) * 32)
            asm volatile("s_waitcnt vmcnt(8)" ::: "memory");
        } else {
            asm volatile("s_waitcnt vmcnt(0)" ::: "memory");
        }
        __builtin_amdgcn_s_barrier();
        __builtin_amdgcn_sched_barrier(0);

        bf16x8 ah[4], bh[4], al[4], bl[4];
#pragma unroll
        for (int i = 0; i < 4; ++i) {
            ah[i] = *(const bf16x8*)&smem[base + (wm + i * 16 + m16) * 32 + swzf];
            bh[i] = *(const bf16x8*)&smem[base + 4096 + (wn + i * 16 + m16) * 32 + swzf];
            al[i] = *(const bf16x8*)&smem[base + 8192 + (wm + i * 16 + m16) * 32 + swzf];
            bl[i] = *(const bf16x8*)&smem[base + 12288 + (wn + i * 16 + m16) * 32 + swzf];
        }
        __builtin_amdgcn_s_setprio(1);
#pragma unroll
        for (int i = 0; i < 4; ++i)
#pragma unroll
            for (int j = 0; j < 4; ++j) {
                acc[i][j] = __builtin_amdgcn_mfma_f32_16x16x32_bf16(ah[i], bh[j], acc[i][j], 0, 0, 0);
                acc[i][j] = __builtin_amdgcn_mfma_f32_16x16x32_bf16(ah[i], bl[j], acc[i][j], 0, 0, 0);
                acc[i][j] = __builtin_amdgcn_mfma_f32_16x16x32_bf16(al[i], bh[j], acc[i][j], 0, 0, 0);
            }
        __builtin_amdgcn_s_setprio(0);
        base = nbase;
    }
#undef SPLIT_STAGE

#pragma unroll
    for (int i = 0; i < 4; ++i)
#pragma unroll
        for (int r = 0; r < 4; ++r) {
            size_t grow = bm + wm + i * 16 + q * 4 + r;
            float* crow = C + grow * DD + bn + wn + m16;
#pragma unroll
            for (int j = 0; j < 4; ++j) crow[j * 16] = acc[i][j][r];
        }
}

// ---------------------------------------------------------------------------
// LDS param staging: sp = [b1 | g | be | W2row0 | W2row1], 5*2048 floats = 40KB.
__device__ inline void stage_params(float* __restrict__ sp,
                                    const float* __restrict__ b1,
                                    const float* __restrict__ g,
                                    const float* __restrict__ be,
                                    const float* __restrict__ W2, int tid) {
#pragma unroll
    for (int k = 0; k < 2; ++k) {
        int idx = (k * 256 + tid) * 4;             // 0..2047
        *(float4*)&sp[idx]          = *(const float4*)&b1[idx];
        *(float4*)&sp[2048 + idx]   = *(const float4*)&g[idx];
        *(float4*)&sp[4096 + idx]   = *(const float4*)&be[idx];
        *(float4*)&sp[6144 + idx]   = *(const float4*)&W2[idx];
        *(float4*)&sp[8192 + idx]   = *(const float4*)&W2[2048 + idx];
    }
}

// ---------------------------------------------------------------------------
// One row per wave per call. h row held in 16 VGPRs (4 x uint4); conversion
// recomputed in pass 2 -> no v[32] array, no reloads, no spills. Params from
// LDS (ds_read_b128, conflict-free: 16 B/lane stride). Scalars only across
// this boundary.
__device__ inline void ln_row(const u16* __restrict__ hr,
                              const float* __restrict__ sp,
                              int lane, float b20, float b21,
                              float& L0, float& L1) {
    const int cb = lane * 8;
    uint4 h0 = *(const uint4*)(hr + 0 * 512 + cb);
    uint4 h1 = *(const uint4*)(hr + 1 * 512 + cb);
    uint4 h2 = *(const uint4*)(hr + 2 * 512 + cb);
    uint4 h3 = *(const uint4*)(hr + 3 * 512 + cb);

    float sum = 0.f, sumsq = 0.f;
#define LN_STATS(HV, C)                                                        \
    {                                                                          \
        int col = (C) * 512 + cb;                                              \
        float4 b0 = *(const float4*)(sp + col);                                \
        float4 b4 = *(const float4*)(sp + col + 4);                            \
        float f0, f1, f2, f3, f4, f5, f6, f7;                                  \
        bf2x2(HV.x, f0, f1); bf2x2(HV.y, f2, f3);                              \
        bf2x2(HV.z, f4, f5); bf2x2(HV.w, f6, f7);                              \
        f0 += b0.x; f1 += b0.y; f2 += b0.z; f3 += b0.w;                        \
        f4 += b4.x; f5 += b4.y; f6 += b4.z; f7 += b4.w;                        \
        sum += ((f0 + f1) + (f2 + f3)) + ((f4 + f5) + (f6 + f7));              \
        sumsq += ((f0 * f0 + f1 * f1) + (f2 * f2 + f3 * f3)) +                 \
                 ((f4 * f4 + f5 * f5) + (f6 * f6 + f7 * f7));                  \
    }
    LN_STATS(h0, 0) LN_STATS(h1, 1) LN_STATS(h2, 2) LN_STATS(h3, 3)
#undef LN_STATS
#pragma unroll
    for (int off = 32; off > 0; off >>= 1) {
        sum += __shfl_xor(sum, off);
        sumsq += __shfl_xor(sumsq, off);
    }
    const float mu = sum * (1.f / 2048.f);
    const float var = sumsq * (1.f / 2048.f) - mu * mu;
    const float rstd = rsqrtf(var + LN_EPS);

    float l0 = 0.f, l1 = 0.f;
#define LN_HEAD(HV, C)                                                         \
    {                                                                          \
        int col = (C) * 512 + cb;                                              \
        float4 b0 = *(const float4*)(sp + col);                                \
        float4 b4 = *(const float4*)(sp + col + 4);                            \
        float4 g0 = *(const float4*)(sp + 2048 + col);                         \
        float4 g4 = *(const float4*)(sp + 2048 + col + 4);                     \
        float4 e0 = *(const float4*)(sp + 4096 + col);                         \
        float4 e4 = *(const float4*)(sp + 4096 + col + 4);                     \
        float4 w00 = *(const float4*)(sp + 6144 + col);                        \
        float4 w04 = *(const float4*)(sp + 6144 + col + 4);                    \
        float4 w10 = *(const float4*)(sp + 8192 + col);                        \
        float4 w14 = *(const float4*)(sp + 8192 + col + 4);                    \
        float f0, f1, f2, f3, f4, f5, f6, f7, hn;                              \
        bf2x2(HV.x, f0, f1); bf2x2(HV.y, f2, f3);                              \
        bf2x2(HV.z, f4, f5); bf2x2(HV.w, f6, f7);                              \
        hn = fmaxf(((f0 + b0.x) - mu) * rstd * g0.x + e0.x, 0.f); l0 += hn * w00.x; l1 += hn * w10.x; \
        hn = fmaxf(((f1 + b0.y) - mu) * rstd * g0.y + e0.y, 0.f); l0 += hn * w00.y; l1 += hn * w10.y; \
        hn = fmaxf(((f2 + b0.z) - mu) * rstd * g0.z + e0.z, 0.f); l0 += hn * w00.z; l1 += hn * w10.z; \
        hn = fmaxf(((f3 + b0.w) - mu) * rstd * g0.w + e0.w, 0.f); l0 += hn * w00.w; l1 += hn * w10.w; \
        hn = fmaxf(((f4 + b4.x) - mu) * rstd * g4.x + e4.x, 0.f); l0 += hn * w04.x; l1 += hn * w14.x; \
        hn = fmaxf(((f5 + b4.y) - mu) * rstd * g4.y + e4.y, 0.f); l0 += hn * w04.y; l1 += hn * w14.y; \
        hn = fmaxf(((f6 + b4.z) - mu) * rstd * g4.z + e4.z, 0.f); l0 += hn * w04.z; l1 += hn * w14.z; \
        hn = fmaxf(((f7 + b4.w) - mu) * rstd * g4.w + e4.w, 0.f); l0 += hn * w04.w; l1 += hn * w14.w; \
    }
    LN_HEAD(h0, 0) LN_HEAD(h1, 1) LN_HEAD(h2, 2) LN_HEAD(h3, 3)
#undef LN_HEAD
#pragma unroll
    for (int off = 32; off > 0; off >>= 1) {
        l0 += __shfl_xor(l0, off);
        l1 += __shfl_xor(l1, off);
    }
    L0 = l0 + b20;
    L1 = l1 + b21;
}

// fp32-h LN core (fixup path only, few rows)
__device__ inline void ln_core(const float* __restrict__ hr,
                               const float* __restrict__ b1,
                               const float* __restrict__ g,
                               const float* __restrict__ be,
                               const float* __restrict__ W2,
                               const float* __restrict__ b2,
                               int lane, float& L0, float& L1) {
    float v[32];
    float sum = 0.f, sumsq = 0.f;
#pragma unroll
    for (int i = 0; i < 8; ++i) {
        int col = i * 256 + lane * 4;
        float4 t = *(const float4*)(hr + col);
        float4 bb = *(const float4*)(b1 + col);
        t.x += bb.x; t.y += bb.y; t.z += bb.z; t.w += bb.w;
        v[i * 4 + 0] = t.x; v[i * 4 + 1] = t.y; v[i * 4 + 2] = t.z; v[i * 4 + 3] = t.w;
        sum += t.x + t.y + t.z + t.w;
        sumsq += t.x * t.x + t.y * t.y + t.z * t.z + t.w * t.w;
    }
#pragma unroll
    for (int off = 32; off > 0; off >>= 1) {
        sum += __shfl_xor(sum, off);
        sumsq += __shfl_xor(sumsq, off);
    }
    const float mu = sum * (1.f / 2048.f);
    const float var = sumsq * (1.f / 2048.f) - mu * mu;
    const float rstd = rsqrtf(var + LN_EPS);

    float l0 = 0.f, l1 = 0.f;
#pragma unroll
    for (int i = 0; i < 8; ++i) {
        int col = i * 256 + lane * 4;
        float4 gg = *(const float4*)(g + col);
        float4 bbe = *(const float4*)(be + col);
        float4 w0 = *(const float4*)(W2 + col);
        float4 w1 = *(const float4*)(W2 + DD + col);
        float hn;
        hn = fmaxf((v[i * 4 + 0] - mu) * rstd * gg.x + bbe.x, 0.f); l0 += hn * w0.x; l1 += hn * w1.x;
        hn = fmaxf((v[i * 4 + 1] - mu) * rstd * gg.y + bbe.y, 0.f); l0 += hn * w0.y; l1 += hn * w1.y;
        hn = fmaxf((v[i * 4 + 2] - mu) * rstd * gg.z + bbe.z, 0.f); l0 += hn * w0.z; l1 += hn * w1.z;
        hn = fmaxf((v[i * 4 + 3] - mu) * rstd * gg.w + bbe.w, 0.f); l0 += hn * w0.w; l1 += hn * w1.w;
    }
#pragma unroll
    for (int off = 32; off > 0; off >>= 1) {
        l0 += __shfl_xor(l0, off);
        l1 += __shfl_xor(l1, off);
    }
    L0 = l0 + b2[0];
    L1 = l1 + b2[1];
}

// Branch-1: route = argmax, count nf (block-aggregated), flag near-ties.
// 2048 blocks x 16 rows (4 rows per wave) -> params staged once per 16 rows
// (8x less staging traffic than 1 block = 4 rows).
__global__ __launch_bounds__(256) void ln_route(const u16* __restrict__ h,
                                                const float* __restrict__ b1,
                                                const float* __restrict__ g,
                                                const float* __restrict__ be,
                                                const float* __restrict__ W2,
                                                const float* __restrict__ b2,
                                                int* __restrict__ route,
                                                int* __restrict__ ctrl,
                                                int* __restrict__ u_idx) {
    __shared__ float sp[5 * 2048];
    __shared__ int blk_nf;
    const int tid = threadIdx.x;
    if (tid == 0) blk_nf = 0;
    stage_params(sp, b1, g, be, W2, tid);
    __syncthreads();
    const int wave = tid >> 6, lane = tid & 63;
    const float b20 = b2[0], b21 = b2[1];
    const int rbase = blockIdx.x * 16 + wave * 4;
    int local_nf = 0;
#pragma unroll
    for (int k = 0; k < 4; ++k) {
        const int r = rbase + k;
        float l0, l1;
        ln_row(h + (size_t)r * DD, sp, lane, b20, b21, l0, l1);
        if (lane == 0) {
            int rt = (l0 >= l1) ? 0 : 1;
            route[r] = rt;
            local_nf += (rt == 0);
            if (fabsf(l0 - l1) < MARGIN) {
                int p = atomicAdd(&ctrl[1], 1);
                if (p < UCAP) u_idx[p] = r;
            }
        }
    }
    if (lane == 0 && local_nf) atomicAdd(&blk_nf, local_nf);
    __syncthreads();
    if (tid == 0 && blk_nf) atomicAdd(&ctrl[0], blk_nf);
}

// Recheck flagged rows with split-precision h (fp32, gathered order).
__global__ __launch_bounds__(256) void ln_fixup(const float* __restrict__ h,
                                                const float* __restrict__ b1,
                                                const float* __restrict__ g,
                                                const float* __restrict__ be,
                                                const float* __restrict__ W2,
                                                const float* __restrict__ b2,
                                                int* __restrict__ route,
                                                int* __restrict__ ctrl,
                                                const int* __restrict__ u_idx) {
    const int wave = threadIdx.x >> 6, lane = threadIdx.x & 63;
    const int r = blockIdx.x * 4 + wave;
    int u = ctrl[1]; if (u > UCAP) u = UCAP;
    if (r >= u) return;
    const int orig = u_idx[r];
    float l0, l1;
    ln_core(h + (size_t)r * DD, b1, g, be, W2, b2, lane, l0, l1);
    if (lane == 0) {
        int rt = (l0 >= l1) ? 0 : 1;
        int old = route[orig];
        if (rt != old) {
            atomicAdd(&ctrl[0], rt == 0 ? 1 : -1);
            route[orig] = rt;
        }
    }
}

__global__ void init_ctrl(int* ctrl) {
    int nf = ctrl[0];
    ctrl[2] = nf;
    ctrl[3] = (nf + 255) & ~255;                   // 256-aligned (256-row GEMM tiles)
    ctrl[4] = 0;
    ctrl[5] = ctrl[3];
}

// Compact rows: fake segment at [0,nf), real segment at [nf_pad, nf_pad+nr).
__global__ __launch_bounds__(256) void compact(const int* __restrict__ route,
                                               int* __restrict__ ctrl,
                                               int* __restrict__ idx_all) {
    const int row = blockIdx.x * 256 + threadIdx.x;
    const int lane = threadIdx.x & 63;
    const bool isf = (route[row] == 0);
    unsigned long long m = __ballot(isf);
    int nfw = __popcll(m);
    int baseF = 0, baseR = 0;
    if (lane == 0) {
        baseF = atomicAdd(&ctrl[4], nfw);
        baseR = atomicAdd(&ctrl[5], 64 - nfw);
    }
    baseF = __shfl(baseF, 0);
    baseR = __shfl(baseR, 0);
    unsigned long long lt = (lane == 0) ? 0ull : ((~0ull) >> (64 - lane));
    int pre = __popcll(m & lt);
    int pos = isf ? (baseF + pre) : (baseR + (lane - pre));
    idx_all[pos] = row;
}

// Final pass over combined gathered bf16 h. 16 rows per block (4 per wave).
// Real segment starts 256-aligned (nf_pad) and 16 | 256 -> no block straddles
// the real-segment start; fake-edge blocks guard per-row. Gap blocks return.
__global__ __launch_bounds__(256) void ln_final(const u16* __restrict__ h,
                                                const float* __restrict__ b1f, const float* __restrict__ gf,
                                                const float* __restrict__ bef, const float* __restrict__ W2f,
                                                const float* __restrict__ b2f,
                                                const float* __restrict__ b1r, const float* __restrict__ gr,
                                                const float* __restrict__ ber, const float* __restrict__ W2r,
                                                const float* __restrict__ b2r,
                                                const int* __restrict__ ctrl,
                                                const int* __restrict__ idx_all,
                                                float* __restrict__ out) {
    const int nf = ctrl[2], nf_pad = ctrl[3];
    const int limit = nf_pad + (BD - nf);
    const int base = blockIdx.x * 16;
    bool fake;
    if (base < nf) fake = true;
    else if (base >= nf_pad && base < limit) fake = false;
    else return;                                   // gap / beyond-limit blocks (uniform)
    const int bound = fake ? nf : limit;

    __shared__ float sp[5 * 2048];
    const int tid = threadIdx.x;
    stage_params(sp, fake ? b1f : b1r, fake ? gf : gr, fake ? bef : ber,
                 fake ? W2f : W2r, tid);
    __syncthreads();
    const int wave = tid >> 6, lane = tid & 63;
    const float* b2 = fake ? b2f : b2r;
    const float b20 = b2[0], b21 = b2[1];
    const int rbase = base + wave * 4;
#pragma unroll
    for (int k = 0; k < 4; ++k) {
        const int r = rbase + k;
        if (r >= bound) break;                     // wave-uniform
        float l0, l1;
        ln_row(h + (size_t)r * DD, sp, lane, b20, b21, l0, l1);
        if (lane == 0) {
            int orig = idx_all[r];
            out[(size_t)orig * 2 + 0] = l0;
            out[(size_t)orig * 2 + 1] = l1;
        }
    }
}

extern "C" void kernel_launch(void* const* d_in, const int* in_sizes, int n_in,
                              void* d_out, int out_size, void* d_ws, size_t ws_size,
                              hipStream_t stream) {
    const float* x = (const float*)d_in[0];
    const float* W1[3] = {(const float*)d_in[1], (const float*)d_in[7], (const float*)d_in[13]};
    const float* b1[3] = {(const float*)d_in[2], (const float*)d_in[8], (const float*)d_in[14]};
    const float* lg[3] = {(const float*)d_in[3], (const float*)d_in[9], (const float*)d_in[15]};
    const float* lb[3] = {(const float*)d_in[4], (const float*)d_in[10], (const float*)d_in[16]};
    const float* W2[3] = {(const float*)d_in[5], (const float*)d_in[11], (const float*)d_in[17]};
    const float* b2[3] = {(const float*)d_in[6], (const float*)d_in[12], (const float*)d_in[18]};

    char* ws = (char*)d_ws;
    size_t off = 0;
    u16* x_hi = (u16*)(ws + off); off += (size_t)BD * DD * 2;        // 134 MB
    u16* x_lo = (u16*)(ws + off); off += (size_t)UCAP * DD * 2;      // 32 MB (compact, flagged rows)
    u16* w_hi[3];
    u16* w_lo[3];
    for (int i = 0; i < 3; ++i) { w_hi[i] = (u16*)(ws + off); off += (size_t)DD * DD * 2; }
    for (int i = 0; i < 3; ++i) { w_lo[i] = (u16*)(ws + off); off += (size_t)DD * DD * 2; }
    u16* h16 = (u16*)(ws + off); off += (size_t)IDX_CAP * DD * 2;    // 136 MB
    float* hfix = (float*)(ws + off); off += (size_t)UCAP * DD * 4;  // 67 MB
    int* route = (int*)(ws + off); off += (size_t)BD * 4;
    int* idx_all = (int*)(ws + off); off += (size_t)IDX_CAP * 4;
    int* u_idx = (int*)(ws + off); off += (size_t)UCAP * 4;
    int* ctrl = (int*)(ws + off); off += 64;

    // 0) zero control/index buffers (ws is poisoned each replay)
    zero_misc<<<(IDX_CAP + 255) / 256, 256, 0, stream>>>(idx_all, u_idx, ctrl);

    // 1) precision splits (x hi-only; all three W1 in one launch)
    split_xhi<<<(BD * DD / 4) / 256, 256, 0, stream>>>(x, x_hi, BD * DD / 4);
    split_w3<<<dim3((DD * DD / 4) / 256, 3), 256, 0, stream>>>(
        W1[0], W1[1], W1[2], w_hi[0], w_lo[0], w_hi[1], w_lo[1], w_hi[2], w_lo[2]);

    // 2) branch 1 in bf16 (256² r4 counted-pipeline); route + near-tie flags
    gemm256<0, 0><<<dim3(DD / 256, BD / 256), 512, 0, stream>>>(
        x_hi, w_hi[0], nullptr, h16, nullptr, nullptr);
    ln_route<<<BD / 16, 256, 0, stream>>>(h16, b1[0], lg[0], lb[0], W2[0], b2[0],
                                          route, ctrl, u_idx);

    // 3) lo-split for flagged rows only, then split-precision recheck
    split_xlo<<<UCAP, 256, 0, stream>>>(x, u_idx, ctrl, x_lo);
    gemm_split<<<dim3(DD / 128, UCAP / 128), 256, 0, stream>>>(
        x_hi, x_lo, w_hi[0], w_lo[0], hfix, u_idx, ctrl);
    ln_fixup<<<UCAP / 4, 256, 0, stream>>>(hfix, b1[0], lg[0], lb[0], W2[0], b2[0],
                                           route, ctrl, u_idx);

    // 4) compact rows into fake|real segments (256-padded boundary)
    init_ctrl<<<1, 1, 0, stream>>>(ctrl);
    compact<<<BD / 256, 256, 0, stream>>>(route, ctrl, idx_all);

    // 5) one combined gathered GEMM over both segments (per-row-block B select)
    gemm256<1, 1><<<dim3(DD / 256, BD / 256 + 1), 512, 0, stream>>>(
        x_hi, w_hi[1], w_hi[2], h16, idx_all, ctrl);

    // 6) final LN+head, scatter to out by original row
    ln_final<<<IDX_CAP / 16, 256, 0, stream>>>(
        h16, b1[1], lg[1], lb[1], W2[1], b2[1],
        b1[2], lg[2], lb[2], W2[2], b2[2],
        ctrl, idx_all, (float*)d_out);
}